// Round 5
// baseline (370.362 us; speedup 1.0000x reference)
//
#include <hip/hip_runtime.h>
#include <hip/hip_bf16.h>
#include <cstdint>
#include <cstddef>

typedef __attribute__((ext_vector_type(8))) short short8;
typedef __attribute__((ext_vector_type(4))) float f32x4;

#define DEVI static __device__ __forceinline__

DEVI unsigned short f2bf(float f) {
  unsigned u = __float_as_uint(f);
  unsigned r = u + 0x7fffu + ((u >> 16) & 1u);
  return (unsigned short)(r >> 16);
}
DEVI float bf2f(unsigned short s) {
  return __uint_as_float(((unsigned)s) << 16);
}
DEVI unsigned pack2(float a, float b) {
  return (unsigned)f2bf(a) | ((unsigned)f2bf(b) << 16);
}

DEVI void gload16(const void* g, void* l) {
  __builtin_amdgcn_global_load_lds(
      (__attribute__((address_space(1))) void*)g,
      (__attribute__((address_space(3))) void*)l, 16, 0, 0);
}

// ---------------------------------------------------------------------------
// prep_all: fused  x->xb bf16 (blocks 0..16383)  +  weight converts (16384..)
// ---------------------------------------------------------------------------
__global__ __launch_bounds__(256) void prep_all(
    const float* __restrict__ x, const float* __restrict__ Wq,
    const float* __restrict__ Wkv, const float* __restrict__ Wp,
    unsigned short* __restrict__ xb, unsigned short* __restrict__ wcat,
    unsigned short* __restrict__ wpb) {
  int bidx = blockIdx.x;
  if (bidx < 16384) {
    size_t i = ((size_t)bidx * 256 + threadIdx.x) * 8;
    const float4* g = (const float4*)(x + i);
    float4 a = g[0], b = g[1];
    uint4 u;
    u.x = pack2(a.x, a.y);
    u.y = pack2(a.z, a.w);
    u.z = pack2(b.x, b.y);
    u.w = pack2(b.z, b.w);
    *(uint4*)(xb + i) = u;
  } else {
    int i = (bidx - 16384) * 256 + threadIdx.x;
    if (i < 196608) {
      float v = (i < 65536) ? Wq[i] : Wkv[i - 65536];
      wcat[i] = f2bf(v);
    } else {
      int j = i - 196608;
      wpb[j] = f2bf(Wp[j]);
    }
  }
}

// ---------------------------------------------------------------------------
// Persistent GEMM: C[M x Nout] = A[M x 256] * W[Nout x 256]^T, bf16 MFMA.
// 256 blocks (1/CU), 512 threads (8 waves, 2x4 -> wave owns 64x32 of 128x128).
// Per block: runs of jobs sharing a 128-col tile of W. B resident in LDS
// (64 KB, full K); A streamed through ring-4 16KB buffers via global_load_lds
// with counted vmcnt (T3+T4). One barrier per K-step.
// MODE 0: epilogue elu+1 -> Q/K/V bf16.  MODE 1: epilogue + bias -> out fp32.
// ---------------------------------------------------------------------------
template<int MODE>
__global__ __launch_bounds__(512, 2) void gemm_persist(
    const unsigned short* __restrict__ A,
    const unsigned short* __restrict__ Bw,
    unsigned short* __restrict__ Q, unsigned short* __restrict__ Kb,
    unsigned short* __restrict__ Vb, float* __restrict__ out,
    const float* __restrict__ bias, int jobs_per_block) {
  const int t = threadIdx.x;
  const int lane = t & 63, w = t >> 6;   // 8 waves
  const int wm = w >> 2, wn = w & 3;     // 2 x 4
  const int rl = lane >> 3;              // A-stage row-in-seg (0..7)
  const int swcolA = ((lane & 7) ^ rl) << 4;  // pre-swizzled A src col byte
  const int fr = lane & 15, fq = lane >> 4;

  __shared__ __align__(16) unsigned char ldsB[65536];      // [128 rows][512B]
  __shared__ __align__(16) unsigned char ldsA[4][16384];   // ring of 4 K-steps

  f32x4 acc[4][2];

  int g = blockIdx.x * jobs_per_block;
  const int gEnd = g + jobs_per_block;

  while (g < gEnd) {
    const int col = g >> 10;                       // 1024 panels per col tile
    const int runEnd = min(gEnd, (col + 1) << 10);
    const int R = runEnd - g;
    const int p0 = g & 1023;
    const int bcol = col * 128;

    // ---- load B tile (full K=256) once per run: 64 segs of 1KB ----
    {
      const int brow2 = lane >> 5;   // 0/1 within seg
      const int slot = lane & 31;
#pragma unroll
      for (int s = 0; s < 8; ++s) {
        int seg = w * 8 + s;
        int row = seg * 2 + brow2;
        gload16((const char*)Bw + (size_t)(bcol + row) * 512 +
                    ((slot ^ (row & 7)) << 4),
                ldsB + seg * 1024);
      }
    }
#pragma unroll
    for (int i = 0; i < 4; ++i)
#pragma unroll
      for (int j = 0; j < 2; ++j)
#pragma unroll
        for (int c = 0; c < 4; ++c) acc[i][j][c] = 0.f;

    const int S = R * 4;

    auto stageA = [&](int step) {
      int panel = p0 + (step >> 2), kt = step & 3;
#pragma unroll
      for (int s = 0; s < 2; ++s) {
        int seg = w * 2 + s;
        gload16((const char*)A + (size_t)(panel * 128 + seg * 8 + rl) * 512 +
                    kt * 128 + swcolA,
                ldsA[step & 3] + seg * 1024);
      }
    };

    auto compute = [&](int step) {
      int kt = step & 3;
      const unsigned char* bufA = ldsA[step & 3];
#pragma unroll
      for (int kkl = 0; kkl < 2; ++kkl) {
        int ka = kkl * 64 + fq * 16;
        int kb = (kt * 2 + kkl) * 64 + fq * 16;
        short8 af[4], bfv[2];
#pragma unroll
        for (int i = 0; i < 4; ++i) {
          int ra = wm * 64 + i * 16 + fr;
          af[i] = *(const short8*)(bufA + ra * 128 + (ka ^ ((ra & 7) << 4)));
        }
#pragma unroll
        for (int j = 0; j < 2; ++j) {
          int rb = wn * 32 + j * 16 + fr;
          bfv[j] = *(const short8*)(ldsB + rb * 512 + (kb ^ ((rb & 7) << 4)));
        }
#pragma unroll
        for (int i = 0; i < 4; ++i)
#pragma unroll
          for (int j = 0; j < 2; ++j)
            acc[i][j] = __builtin_amdgcn_mfma_f32_16x16x32_bf16(
                af[i], bfv[j], acc[i][j], 0, 0, 0);
      }
    };

    // epilogue target (uniform per run)
    unsigned short* dst = nullptr;
    int cofs = 0;
    bool do_elu = true;
    if (MODE == 0) {
      if (bcol < 256) { dst = Q; cofs = bcol; do_elu = true; }
      else if (bcol < 512) { dst = Kb; cofs = bcol - 256; do_elu = true; }
      else { dst = Vb; cofs = bcol - 512; do_elu = false; }
    }

    auto epilogue = [&](int r) {
      int brow = (p0 + r) * 128;
#pragma unroll
      for (int i = 0; i < 4; ++i)
#pragma unroll
        for (int j = 0; j < 2; ++j) {
#pragma unroll
          for (int reg = 0; reg < 4; ++reg) {
            int gm = brow + wm * 64 + i * 16 + fq * 4 + reg;
            int cn = wn * 32 + j * 16 + fr;
            float val = acc[i][j][reg];
            if (MODE == 0) {
              if (do_elu) val = (val > 0.f) ? (val + 1.f) : __expf(val);
              dst[(size_t)gm * 256 + cofs + cn] = f2bf(val);
            } else {
              out[(size_t)gm * 256 + bcol + cn] = val + bias[bcol + cn];
            }
          }
#pragma unroll
          for (int c = 0; c < 4; ++c) acc[i][j][c] = 0.f;
        }
    };

    // ---- prologue: stage steps 0..2, wait B+s0 ----
    stageA(0); stageA(1); stageA(2);
    asm volatile("s_waitcnt vmcnt(4)" ::: "memory");
    __builtin_amdgcn_s_barrier();

    // ---- main pipeline: one barrier per step, counted vmcnt ----
    for (int i = 0; i <= S - 4; ++i) {
      stageA(i + 3);
      compute(i);
      if ((i & 3) == 3) epilogue(i >> 2);
      if (i < 3) { asm volatile("s_waitcnt vmcnt(4)" ::: "memory"); }
      else       { asm volatile("s_waitcnt vmcnt(36)" ::: "memory"); }
      __builtin_amdgcn_s_barrier();
    }
    // ---- tail: steps S-3, S-2, S-1 (all staged) ----
    compute(S - 3);
    if (R > 1) { asm volatile("s_waitcnt vmcnt(34)" ::: "memory"); }
    else       { asm volatile("s_waitcnt vmcnt(2)" ::: "memory"); }
    __builtin_amdgcn_s_barrier();
    compute(S - 2);
    asm volatile("s_waitcnt vmcnt(0)" ::: "memory");
    __builtin_amdgcn_s_barrier();
    compute(S - 1);
    __builtin_amdgcn_s_barrier();
    epilogue(R - 1);

    g = runEnd;
  }
}

// ---------------------------------------------------------------------------
// Fallback QKV GEMM (fp32 A, reg-stage), 4-wave 128x128 — used only if ws too
// small for the xb buffer. Proven in round 2.
// ---------------------------------------------------------------------------
__global__ __launch_bounds__(256) void gemm_qkv_f32(
    const float* __restrict__ xp, const unsigned short* __restrict__ Bw,
    unsigned short* __restrict__ Q, unsigned short* __restrict__ Kb,
    unsigned short* __restrict__ Vb, int ntiles_n) {
  const int bid = blockIdx.x;
  const int bx = bid % ntiles_n, by = bid / ntiles_n;
  const int brow = by * 128, bcol = bx * 128;
  const int t = threadIdx.x;
  const int lane = t & 63, w = t >> 6;
  const int wm = w >> 1, wn = w & 1;
  __shared__ __align__(16) unsigned char ldsA[128 * 128];
  __shared__ __align__(16) unsigned char ldsB[128 * 128];
  f32x4 acc[4][4] = {};
  const int sub = t & 7, r0 = t >> 3;
  const int fr = lane & 15, fq = lane >> 4;
  for (int kt = 0; kt < 4; ++kt) {
#pragma unroll
    for (int p = 0; p < 4; ++p) {
      int row = p * 32 + r0;
      const float4* gp =
          (const float4*)(xp + (size_t)(brow + row) * 256 + kt * 64 + sub * 8);
      float4 u0 = gp[0], u1 = gp[1];
      uint4 u;
      u.x = pack2(u0.x, u0.y); u.y = pack2(u0.z, u0.w);
      u.z = pack2(u1.x, u1.y); u.w = pack2(u1.z, u1.w);
      *(uint4*)(&ldsA[row * 128 + ((sub * 16) ^ ((row & 7) << 4))]) = u;
    }
#pragma unroll
    for (int p = 0; p < 4; ++p) {
      int row = p * 32 + r0;
      uint4 u = *(const uint4*)(Bw + (size_t)(bcol + row) * 256 + kt * 64 + sub * 8);
      *(uint4*)(&ldsB[row * 128 + ((sub * 16) ^ ((row & 7) << 4))]) = u;
    }
    __syncthreads();
#pragma unroll
    for (int kk = 0; kk < 2; ++kk) {
      int kbyte = kk * 64 + fq * 16;
      short8 af[4], bfr[4];
#pragma unroll
      for (int i = 0; i < 4; ++i) {
        int ra = wm * 64 + i * 16 + fr;
        af[i] = *(const short8*)(&ldsA[ra * 128 + (kbyte ^ ((ra & 7) << 4))]);
        int rb = wn * 64 + i * 16 + fr;
        bfr[i] = *(const short8*)(&ldsB[rb * 128 + (kbyte ^ ((rb & 7) << 4))]);
      }
#pragma unroll
      for (int i = 0; i < 4; ++i)
#pragma unroll
        for (int j = 0; j < 4; ++j)
          acc[i][j] = __builtin_amdgcn_mfma_f32_16x16x32_bf16(af[i], bfr[j],
                                                              acc[i][j], 0, 0, 0);
    }
    __syncthreads();
  }
#pragma unroll
  for (int i = 0; i < 4; ++i)
#pragma unroll
    for (int j = 0; j < 4; ++j)
#pragma unroll
      for (int reg = 0; reg < 4; ++reg) {
        int gm = brow + wm * 64 + i * 16 + fq * 4 + reg;
        int gn = bcol + wn * 64 + j * 16 + fr;
        float val = acc[i][j][reg];
        if (gn < 512) val = (val > 0.f) ? (val + 1.f) : __expf(val);
        unsigned short bv = f2bf(val);
        size_t rowoff = (size_t)gm * 256;
        if (gn < 256) Q[rowoff + gn] = bv;
        else if (gn < 512) Kb[rowoff + gn - 256] = bv;
        else Vb[rowoff + gn - 512] = bv;
      }
}

// ---------------------------------------------------------------------------
// ctx partials: block = (b, head-pair hp, chunk): partial k^T v for 2 heads
// ---------------------------------------------------------------------------
__global__ __launch_bounds__(256) void ctx_partial(
    const unsigned short* __restrict__ Kb, const unsigned short* __restrict__ Vb,
    float* __restrict__ pctx, float* __restrict__ pksum) {
  const int blk = blockIdx.x;
  const int b = blk >> 6;
  const int hp = (blk >> 4) & 3;
  const int chunk = blk & 15;
  const int t = threadIdx.x;
  const size_t rowbase = (size_t)b * 16384 + (size_t)chunk * 1024;
  const int colbase = hp * 64;

  __shared__ __align__(16) unsigned short kt_[64][64];
  __shared__ __align__(16) unsigned short vt_[64][64];

  const int d = t >> 3;
  const int e4 = (t & 7) * 4;
  float a0[4] = {0.f, 0.f, 0.f, 0.f}, a1[4] = {0.f, 0.f, 0.f, 0.f};
  float ks0 = 0.f, ks1 = 0.f;

  const int lrow = t >> 3;
  const int lcol = (t & 7) * 8;
  for (int pass = 0; pass < 16; ++pass) {
#pragma unroll
    for (int hf = 0; hf < 2; ++hf) {
      size_t row = rowbase + pass * 64 + hf * 32 + lrow;
      *(uint4*)&kt_[hf * 32 + lrow][lcol] = *(const uint4*)(Kb + row * 256 + colbase + lcol);
      *(uint4*)&vt_[hf * 32 + lrow][lcol] = *(const uint4*)(Vb + row * 256 + colbase + lcol);
    }
    __syncthreads();
#pragma unroll 4
    for (int n = 0; n < 64; ++n) {
      float k0 = bf2f(kt_[n][d]);
      float k1 = bf2f(kt_[n][32 + d]);
      if ((t & 7) == 0) { ks0 += k0; ks1 += k1; }
      uint2 w0 = *(const uint2*)&vt_[n][e4];
      uint2 w1 = *(const uint2*)&vt_[n][32 + e4];
      float v00 = __uint_as_float(w0.x << 16), v01 = __uint_as_float(w0.x & 0xffff0000u);
      float v02 = __uint_as_float(w0.y << 16), v03 = __uint_as_float(w0.y & 0xffff0000u);
      float v10 = __uint_as_float(w1.x << 16), v11 = __uint_as_float(w1.x & 0xffff0000u);
      float v12 = __uint_as_float(w1.y << 16), v13 = __uint_as_float(w1.y & 0xffff0000u);
      a0[0] += k0 * v00; a0[1] += k0 * v01; a0[2] += k0 * v02; a0[3] += k0 * v03;
      a1[0] += k1 * v10; a1[1] += k1 * v11; a1[2] += k1 * v12; a1[3] += k1 * v13;
    }
    __syncthreads();
  }
  float* p0 = pctx + (size_t)blk * 2048 + d * 32 + e4;
  p0[0] = a0[0]; p0[1] = a0[1]; p0[2] = a0[2]; p0[3] = a0[3];
  float* p1 = p0 + 1024;
  p1[0] = a1[0]; p1[1] = a1[1]; p1[2] = a1[2]; p1[3] = a1[3];
  if ((t & 7) == 0) {
    pksum[blk * 64 + d] = ks0;
    pksum[blk * 64 + 32 + d] = ks1;
  }
}

__global__ __launch_bounds__(256) void ctx_final(
    const float* __restrict__ pctx, const float* __restrict__ pksum,
    float* __restrict__ ctx, float* __restrict__ ksum) {
  int bh = blockIdx.x;
  int b = bh >> 3, h = bh & 7, hp = h >> 1, hh = h & 1;
  int t = threadIdx.x;
  float s0 = 0.f, s1 = 0.f, s2 = 0.f, s3 = 0.f;
  for (int j = 0; j < 16; ++j) {
    const float* p = pctx + ((size_t)((b * 4 + hp) * 16 + j)) * 2048 + hh * 1024 + t * 4;
    s0 += p[0]; s1 += p[1]; s2 += p[2]; s3 += p[3];
  }
  float* c = ctx + ((size_t)bh << 10) + t * 4;
  c[0] = s0; c[1] = s1; c[2] = s2; c[3] = s3;
  if (t < 32) {
    float s = 0.f;
    for (int j = 0; j < 16; ++j) s += pksum[((b * 4 + hp) * 16 + j) * 64 + hh * 32 + t];
    ksum[bh * 32 + t] = s;
  }
}

// ---------------------------------------------------------------------------
// attn: Dinv[r][h] = 1/max(sum_d q[r][h,d]*ksum[h,d], 1e-6) (per-head)
//       attn[r][h,e] = Dinv[r][h] * sum_d q[r][h,d]*ctx[h][d][e]
// ---------------------------------------------------------------------------
__global__ __launch_bounds__(256) void attn_kernel(
    const unsigned short* __restrict__ Q, const float* __restrict__ ctx,
    const float* __restrict__ ksum, unsigned short* __restrict__ attnb) {
  const int t = threadIdx.x;
  const size_t row0 = (size_t)blockIdx.x * 64;
  const int b = (int)(row0 >> 14);
  const int h = t >> 5, e = t & 31;

  __shared__ float qf[64][288];
  __shared__ float ksumL[288];
  __shared__ float Dinv_s[64][8];

  float creg[32];
  const float* cbase = ctx + ((size_t)(b * 8 + h) << 10) + e;
#pragma unroll
  for (int d2 = 0; d2 < 32; ++d2) creg[d2] = cbase[d2 * 32];

  ksumL[h * 36 + e] = ksum[(b * 8 + h) * 32 + e];

  const int rl = t >> 5;
  const int c8 = (t & 31) * 8;
#pragma unroll
  for (int p = 0; p < 8; ++p) {
    int r = p * 8 + rl;
    uint4 u = *(const uint4*)(Q + (row0 + r) * 256 + c8);
    const unsigned short* us = (const unsigned short*)&u;
    float* dstp = &qf[r][(c8 >> 5) * 36 + (c8 & 31)];
#pragma unroll
    for (int q2 = 0; q2 < 8; ++q2) dstp[q2] = bf2f(us[q2]);
  }
  __syncthreads();

#pragma unroll
  for (int ii = 0; ii < 2; ++ii) {
    int idx = t + ii * 256;
    int r = idx >> 3, hh = idx & 7;
    const float* qr = &qf[r][hh * 36];
    const float* ks = &ksumL[hh * 36];
    float s = 0.f;
#pragma unroll
    for (int d2 = 0; d2 < 32; ++d2) s += qr[d2] * ks[d2];
    Dinv_s[r][hh] = 1.f / fmaxf(s, 1e-6f);
  }
  __syncthreads();

  for (int r = 0; r < 64; ++r) {
    const float* qr = &qf[r][h * 36];
    float s = 0.f;
#pragma unroll
    for (int d2 = 0; d2 < 32; ++d2) s += qr[d2] * creg[d2];
    attnb[(row0 + r) * 256 + t] = f2bf(s * Dinv_s[r][h]);
  }
}

// ---------------------------------------------------------------------------
extern "C" void kernel_launch(void* const* d_in, const int* in_sizes, int n_in,
                              void* d_out, int out_size, void* d_ws, size_t ws_size,
                              hipStream_t stream) {
  const float* x = (const float*)d_in[0];
  const float* Wq = (const float*)d_in[1];
  const float* Wkv = (const float*)d_in[2];
  const float* Wproj = (const float*)d_in[3];
  const float* bproj = (const float*)d_in[4];
  float* out = (float*)d_out;

  char* ws = (char*)d_ws;
  unsigned short* Q = (unsigned short*)(ws);                 // 67,108,864
  unsigned short* Kb = (unsigned short*)(ws + 67108864);     // 67,108,864
  unsigned short* Vb = (unsigned short*)(ws + 134217728);    // 67,108,864
  unsigned short* wcat = (unsigned short*)(ws + 201326592);  // 393,216
  unsigned short* wpb = (unsigned short*)(ws + 201719808);   // 131,072
  unsigned short* xb = (unsigned short*)(ws + 201850880);    // 67,108,864 (dead after qkv gemm)
  float* pctx = (float*)(ws + 201850880);                    // aliases xb
  float* pksum = (float*)(ws + 206045184);
  float* ctx = (float*)(ws + 206176256);
  float* ksum = (float*)(ws + 206438400);
  unsigned short* attnb = Kb;  // reuse K buffer after ctx reduction

  const bool big = ws_size >= (size_t)268959744;

  if (big) {
    prep_all<<<17408, 256, 0, stream>>>(x, Wq, Wkv, Wproj, xb, wcat, wpb);
    gemm_persist<0><<<256, 512, 0, stream>>>(xb, wcat, Q, Kb, Vb, nullptr,
                                             nullptr, 24);
  } else {
    prep_all<<<1024, 256, 0, stream>>>(nullptr, Wq, Wkv, Wproj, nullptr, wcat, wpb);
    gemm_qkv_f32<<<6144, 256, 0, stream>>>(x, wcat, Q, Kb, Vb, 6);
  }
  ctx_partial<<<512, 256, 0, stream>>>(Kb, Vb, pctx, pksum);
  ctx_final<<<64, 256, 0, stream>>>(pctx, pksum, ctx, ksum);
  attn_kernel<<<2048, 256, 0, stream>>>(Q, ctx, ksum, attnb);
  gemm_persist<1><<<256, 512, 0, stream>>>(attnb, wpb, nullptr, nullptr, nullptr,
                                           out, bproj, 8);
}

// Round 6
// 332.091 us; speedup vs baseline: 1.1152x; 1.1152x over previous
//
#include <hip/hip_runtime.h>
#include <hip/hip_bf16.h>
#include <cstdint>
#include <cstddef>

typedef __attribute__((ext_vector_type(8))) short short8;
typedef __attribute__((ext_vector_type(4))) float f32x4;

#define DEVI static __device__ __forceinline__

DEVI unsigned short f2bf(float f) {
  unsigned u = __float_as_uint(f);
  unsigned r = u + 0x7fffu + ((u >> 16) & 1u);
  return (unsigned short)(r >> 16);
}
DEVI float bf2f(unsigned short s) {
  return __uint_as_float(((unsigned)s) << 16);
}
DEVI unsigned pack2(float a, float b) {
  return (unsigned)f2bf(a) | ((unsigned)f2bf(b) << 16);
}

DEVI void gload16(const void* g, void* l) {
  __builtin_amdgcn_global_load_lds(
      (__attribute__((address_space(1))) void*)g,
      (__attribute__((address_space(3))) void*)l, 16, 0, 0);
}

// ---------------------------------------------------------------------------
// prep_all: fused  x->xb bf16 (blocks 0..16383)  +  weight converts (16384..)
// ---------------------------------------------------------------------------
__global__ __launch_bounds__(256) void prep_all(
    const float* __restrict__ x, const float* __restrict__ Wq,
    const float* __restrict__ Wkv, const float* __restrict__ Wp,
    unsigned short* __restrict__ xb, unsigned short* __restrict__ wcat,
    unsigned short* __restrict__ wpb) {
  int bidx = blockIdx.x;
  if (bidx < 16384) {
    size_t i = ((size_t)bidx * 256 + threadIdx.x) * 8;
    const float4* g = (const float4*)(x + i);
    float4 a = g[0], b = g[1];
    uint4 u;
    u.x = pack2(a.x, a.y);
    u.y = pack2(a.z, a.w);
    u.z = pack2(b.x, b.y);
    u.w = pack2(b.z, b.w);
    *(uint4*)(xb + i) = u;
  } else {
    int i = (bidx - 16384) * 256 + threadIdx.x;
    if (i < 196608) {
      float v = (i < 65536) ? Wq[i] : Wkv[i - 65536];
      wcat[i] = f2bf(v);
    } else {
      int j = i - 196608;
      wpb[j] = f2bf(Wp[j]);
    }
  }
}

// ---------------------------------------------------------------------------
// GEMM  C[M x Nout] = A[M x 256] * W[Nout x 256]^T, bf16 MFMA 16x16x32
// Round-3 structure (6144/2048-block XCD-swizzled grid, 4 waves, 128x128,
// single-buffered gload_lds) + NEW coalesced epilogue: each wave stages its
// 64x64 C-quadrant through a private 8KB LDS region (XOR-swizzled) and
// stores 16B/lane -> 8 full 128B lines per store instruction.
// MODE 0: epilogue elu+1 -> Q/K/V bf16.   MODE 1: epilogue + bias -> out fp32.
// ---------------------------------------------------------------------------
template<int MODE>
__global__ __launch_bounds__(256) void gemm_bt(
    const unsigned short* __restrict__ A,
    const unsigned short* __restrict__ Bw,
    unsigned short* __restrict__ Q, unsigned short* __restrict__ Kb,
    unsigned short* __restrict__ Vb, float* __restrict__ out,
    const float* __restrict__ bias, int ntiles_n) {
  const int nwg = gridDim.x;  // multiple of 8
  const int cpx = nwg >> 3;
  const int bid = blockIdx.x;
  const int swz = (bid & 7) * cpx + (bid >> 3);
  const int bx = swz % ntiles_n, by = swz / ntiles_n;
  const int brow = by * 128, bcol = bx * 128;
  const int t = threadIdx.x, lane = t & 63, w = t >> 6;
  const int wm = w >> 1, wn = w & 1;
  const int rl = lane >> 3;                    // row-in-seg 0..7
  const int swcol = (((lane & 7) ^ rl) << 4);  // pre-swizzled src col byte
  const int fr = lane & 15, fq = lane >> 4;

  __shared__ __align__(16) unsigned char lds[32768];
  unsigned char* ldsA = lds;
  unsigned char* ldsB = lds + 16384;

  f32x4 acc[4][4] = {};

  float bias_r[4];
  if (MODE == 1) {
#pragma unroll
    for (int j = 0; j < 4; ++j) bias_r[j] = bias[bcol + wn * 64 + j * 16 + fr];
  }

  for (int kt = 0; kt < 4; ++kt) {
#pragma unroll
    for (int s = 0; s < 4; ++s) {
      int row = w * 32 + s * 8;  // wave-uniform seg base
      gload16((const char*)(A + (size_t)(brow + row + rl) * 256) + kt * 128 + swcol,
              ldsA + row * 128);
      gload16((const char*)(Bw + (size_t)(bcol + row + rl) * 256) + kt * 128 + swcol,
              ldsB + row * 128);
    }
    __syncthreads();
#pragma unroll
    for (int kk = 0; kk < 2; ++kk) {
      int kbyte = kk * 64 + fq * 16;
      short8 af[4], bfr[4];
#pragma unroll
      for (int i = 0; i < 4; ++i) {
        int ra = wm * 64 + i * 16 + fr;
        af[i] = *(const short8*)(ldsA + ra * 128 + (kbyte ^ ((ra & 7) << 4)));
        int rb = wn * 64 + i * 16 + fr;
        bfr[i] = *(const short8*)(ldsB + rb * 128 + (kbyte ^ ((rb & 7) << 4)));
      }
#pragma unroll
      for (int i = 0; i < 4; ++i)
#pragma unroll
        for (int j = 0; j < 4; ++j)
          acc[i][j] = __builtin_amdgcn_mfma_f32_16x16x32_bf16(af[i], bfr[j],
                                                              acc[i][j], 0, 0, 0);
    }
    __syncthreads();  // protects LDS reuse (next stage / epilogue scratch)
  }

  // --- coalesced epilogue: wave-private 8KB LDS region ---
  unsigned char* wlds = lds + w * 8192;

  if (MODE == 0) {
    unsigned short* dst;
    int cofs;
    bool do_elu;
    if (bcol < 256) { dst = Q; cofs = bcol; do_elu = true; }
    else if (bcol < 512) { dst = Kb; cofs = bcol - 256; do_elu = true; }
    else { dst = Vb; cofs = bcol - 512; do_elu = false; }

    // writer: 64 x ds_write_b16, XOR-swizzled rows (row-major [64][128B])
#pragma unroll
    for (int i = 0; i < 4; ++i)
#pragma unroll
      for (int j = 0; j < 4; ++j)
#pragma unroll
        for (int reg = 0; reg < 4; ++reg) {
          int rloc = i * 16 + fq * 4 + reg;
          int cb = (j * 16 + fr) * 2;
          float val = acc[i][j][reg];
          if (do_elu) val = (val > 0.f) ? (val + 1.f) : __expf(val);
          *(unsigned short*)(wlds + rloc * 128 + (cb ^ ((rloc & 7) << 4))) =
              f2bf(val);
        }
    // reader: 8 x ds_read_b128 -> 8 x global_store_dwordx4 (8x128B lines each)
#pragma unroll
    for (int s = 0; s < 8; ++s) {
      int rloc = s * 8 + (lane >> 3);
      int cbr = (lane & 7) * 16;
      uint4 u = *(const uint4*)(wlds + rloc * 128 + (cbr ^ ((rloc & 7) << 4)));
      *(uint4*)((char*)dst +
                ((size_t)(brow + wm * 64 + rloc) * 256 + cofs + wn * 64) * 2 +
                cbr) = u;
    }
  } else {
    // fp32 out: two 32-col halves (8KB each per wave)
#pragma unroll
    for (int hh = 0; hh < 2; ++hh) {
#pragma unroll
      for (int i = 0; i < 4; ++i)
#pragma unroll
        for (int jj = 0; jj < 2; ++jj) {
          int j = hh * 2 + jj;
#pragma unroll
          for (int reg = 0; reg < 4; ++reg) {
            int rloc = i * 16 + fq * 4 + reg;
            int cb = (jj * 16 + fr) * 4;
            float val = acc[i][j][reg] + bias_r[j];
            *(float*)(wlds + rloc * 128 + (cb ^ ((rloc & 7) << 4))) = val;
          }
        }
#pragma unroll
      for (int s = 0; s < 8; ++s) {
        int rloc = s * 8 + (lane >> 3);
        int cbr = (lane & 7) * 16;
        uint4 u = *(const uint4*)(wlds + rloc * 128 + (cbr ^ ((rloc & 7) << 4)));
        *(uint4*)((char*)out +
                  ((size_t)(brow + wm * 64 + rloc) * 256 + bcol + wn * 64 +
                   hh * 32) * 4 + cbr) = u;
      }
    }
  }
}

// ---------------------------------------------------------------------------
// Fallback QKV GEMM (fp32 A, reg-stage) — only if ws too small for xb.
// ---------------------------------------------------------------------------
__global__ __launch_bounds__(256) void gemm_qkv_f32(
    const float* __restrict__ xp, const unsigned short* __restrict__ Bw,
    unsigned short* __restrict__ Q, unsigned short* __restrict__ Kb,
    unsigned short* __restrict__ Vb, int ntiles_n) {
  const int bid = blockIdx.x;
  const int bx = bid % ntiles_n, by = bid / ntiles_n;
  const int brow = by * 128, bcol = bx * 128;
  const int t = threadIdx.x;
  const int lane = t & 63, w = t >> 6;
  const int wm = w >> 1, wn = w & 1;
  __shared__ __align__(16) unsigned char ldsA[128 * 128];
  __shared__ __align__(16) unsigned char ldsB[128 * 128];
  f32x4 acc[4][4] = {};
  const int sub = t & 7, r0 = t >> 3;
  const int fr = lane & 15, fq = lane >> 4;
  for (int kt = 0; kt < 4; ++kt) {
#pragma unroll
    for (int p = 0; p < 4; ++p) {
      int row = p * 32 + r0;
      const float4* gp =
          (const float4*)(xp + (size_t)(brow + row) * 256 + kt * 64 + sub * 8);
      float4 u0 = gp[0], u1 = gp[1];
      uint4 u;
      u.x = pack2(u0.x, u0.y); u.y = pack2(u0.z, u0.w);
      u.z = pack2(u1.x, u1.y); u.w = pack2(u1.z, u1.w);
      *(uint4*)(&ldsA[row * 128 + ((sub * 16) ^ ((row & 7) << 4))]) = u;
    }
#pragma unroll
    for (int p = 0; p < 4; ++p) {
      int row = p * 32 + r0;
      uint4 u = *(const uint4*)(Bw + (size_t)(bcol + row) * 256 + kt * 64 + sub * 8);
      *(uint4*)(&ldsB[row * 128 + ((sub * 16) ^ ((row & 7) << 4))]) = u;
    }
    __syncthreads();
#pragma unroll
    for (int kk = 0; kk < 2; ++kk) {
      int kbyte = kk * 64 + fq * 16;
      short8 af[4], bfr[4];
#pragma unroll
      for (int i = 0; i < 4; ++i) {
        int ra = wm * 64 + i * 16 + fr;
        af[i] = *(const short8*)(&ldsA[ra * 128 + (kbyte ^ ((ra & 7) << 4))]);
        int rb = wn * 64 + i * 16 + fr;
        bfr[i] = *(const short8*)(&ldsB[rb * 128 + (kbyte ^ ((rb & 7) << 4))]);
      }
#pragma unroll
      for (int i = 0; i < 4; ++i)
#pragma unroll
        for (int j = 0; j < 4; ++j)
          acc[i][j] = __builtin_amdgcn_mfma_f32_16x16x32_bf16(af[i], bfr[j],
                                                              acc[i][j], 0, 0, 0);
    }
    __syncthreads();
  }
#pragma unroll
  for (int i = 0; i < 4; ++i)
#pragma unroll
    for (int j = 0; j < 4; ++j)
#pragma unroll
      for (int reg = 0; reg < 4; ++reg) {
        int gm = brow + wm * 64 + i * 16 + fq * 4 + reg;
        int gn = bcol + wn * 64 + j * 16 + fr;
        float val = acc[i][j][reg];
        if (gn < 512) val = (val > 0.f) ? (val + 1.f) : __expf(val);
        unsigned short bv = f2bf(val);
        size_t rowoff = (size_t)gm * 256;
        if (gn < 256) Q[rowoff + gn] = bv;
        else if (gn < 512) Kb[rowoff + gn - 256] = bv;
        else Vb[rowoff + gn - 512] = bv;
      }
}

// ---------------------------------------------------------------------------
// ctx partials: block = (b, head-pair hp, chunk): partial k^T v for 2 heads
// ---------------------------------------------------------------------------
__global__ __launch_bounds__(256) void ctx_partial(
    const unsigned short* __restrict__ Kb, const unsigned short* __restrict__ Vb,
    float* __restrict__ pctx, float* __restrict__ pksum) {
  const int blk = blockIdx.x;
  const int b = blk >> 6;
  const int hp = (blk >> 4) & 3;
  const int chunk = blk & 15;
  const int t = threadIdx.x;
  const size_t rowbase = (size_t)b * 16384 + (size_t)chunk * 1024;
  const int colbase = hp * 64;

  __shared__ __align__(16) unsigned short kt_[64][64];
  __shared__ __align__(16) unsigned short vt_[64][64];

  const int d = t >> 3;
  const int e4 = (t & 7) * 4;
  float a0[4] = {0.f, 0.f, 0.f, 0.f}, a1[4] = {0.f, 0.f, 0.f, 0.f};
  float ks0 = 0.f, ks1 = 0.f;

  const int lrow = t >> 3;
  const int lcol = (t & 7) * 8;
  for (int pass = 0; pass < 16; ++pass) {
#pragma unroll
    for (int hf = 0; hf < 2; ++hf) {
      size_t row = rowbase + pass * 64 + hf * 32 + lrow;
      *(uint4*)&kt_[hf * 32 + lrow][lcol] = *(const uint4*)(Kb + row * 256 + colbase + lcol);
      *(uint4*)&vt_[hf * 32 + lrow][lcol] = *(const uint4*)(Vb + row * 256 + colbase + lcol);
    }
    __syncthreads();
#pragma unroll 4
    for (int n = 0; n < 64; ++n) {
      float k0 = bf2f(kt_[n][d]);
      float k1 = bf2f(kt_[n][32 + d]);
      if ((t & 7) == 0) { ks0 += k0; ks1 += k1; }
      uint2 w0 = *(const uint2*)&vt_[n][e4];
      uint2 w1 = *(const uint2*)&vt_[n][32 + e4];
      float v00 = __uint_as_float(w0.x << 16), v01 = __uint_as_float(w0.x & 0xffff0000u);
      float v02 = __uint_as_float(w0.y << 16), v03 = __uint_as_float(w0.y & 0xffff0000u);
      float v10 = __uint_as_float(w1.x << 16), v11 = __uint_as_float(w1.x & 0xffff0000u);
      float v12 = __uint_as_float(w1.y << 16), v13 = __uint_as_float(w1.y & 0xffff0000u);
      a0[0] += k0 * v00; a0[1] += k0 * v01; a0[2] += k0 * v02; a0[3] += k0 * v03;
      a1[0] += k1 * v10; a1[1] += k1 * v11; a1[2] += k1 * v12; a1[3] += k1 * v13;
    }
    __syncthreads();
  }
  float* p0 = pctx + (size_t)blk * 2048 + d * 32 + e4;
  p0[0] = a0[0]; p0[1] = a0[1]; p0[2] = a0[2]; p0[3] = a0[3];
  float* p1 = p0 + 1024;
  p1[0] = a1[0]; p1[1] = a1[1]; p1[2] = a1[2]; p1[3] = a1[3];
  if ((t & 7) == 0) {
    pksum[blk * 64 + d] = ks0;
    pksum[blk * 64 + 32 + d] = ks1;
  }
}

__global__ __launch_bounds__(256) void ctx_final(
    const float* __restrict__ pctx, const float* __restrict__ pksum,
    float* __restrict__ ctx, float* __restrict__ ksum) {
  int bh = blockIdx.x;
  int b = bh >> 3, h = bh & 7, hp = h >> 1, hh = h & 1;
  int t = threadIdx.x;
  float s0 = 0.f, s1 = 0.f, s2 = 0.f, s3 = 0.f;
  for (int j = 0; j < 16; ++j) {
    const float* p = pctx + ((size_t)((b * 4 + hp) * 16 + j)) * 2048 + hh * 1024 + t * 4;
    s0 += p[0]; s1 += p[1]; s2 += p[2]; s3 += p[3];
  }
  float* c = ctx + ((size_t)bh << 10) + t * 4;
  c[0] = s0; c[1] = s1; c[2] = s2; c[3] = s3;
  if (t < 32) {
    float s = 0.f;
    for (int j = 0; j < 16; ++j) s += pksum[((b * 4 + hp) * 16 + j) * 64 + hh * 32 + t];
    ksum[bh * 32 + t] = s;
  }
}

// ---------------------------------------------------------------------------
// attn: Dinv[r][h] = 1/max(sum_d q[r][h,d]*ksum[h,d], 1e-6) (per-head)
//       attn[r][h,e] = Dinv[r][h] * sum_d q[r][h,d]*ctx[h][d][e]
// ---------------------------------------------------------------------------
__global__ __launch_bounds__(256) void attn_kernel(
    const unsigned short* __restrict__ Q, const float* __restrict__ ctx,
    const float* __restrict__ ksum, unsigned short* __restrict__ attnb) {
  const int t = threadIdx.x;
  const size_t row0 = (size_t)blockIdx.x * 64;
  const int b = (int)(row0 >> 14);
  const int h = t >> 5, e = t & 31;

  __shared__ float qf[64][288];
  __shared__ float ksumL[288];
  __shared__ float Dinv_s[64][8];

  float creg[32];
  const float* cbase = ctx + ((size_t)(b * 8 + h) << 10) + e;
#pragma unroll
  for (int d2 = 0; d2 < 32; ++d2) creg[d2] = cbase[d2 * 32];

  ksumL[h * 36 + e] = ksum[(b * 8 + h) * 32 + e];

  const int rl = t >> 5;
  const int c8 = (t & 31) * 8;
#pragma unroll
  for (int p = 0; p < 8; ++p) {
    int r = p * 8 + rl;
    uint4 u = *(const uint4*)(Q + (row0 + r) * 256 + c8);
    const unsigned short* us = (const unsigned short*)&u;
    float* dstp = &qf[r][(c8 >> 5) * 36 + (c8 & 31)];
#pragma unroll
    for (int q2 = 0; q2 < 8; ++q2) dstp[q2] = bf2f(us[q2]);
  }
  __syncthreads();

#pragma unroll
  for (int ii = 0; ii < 2; ++ii) {
    int idx = t + ii * 256;
    int r = idx >> 3, hh = idx & 7;
    const float* qr = &qf[r][hh * 36];
    const float* ks = &ksumL[hh * 36];
    float s = 0.f;
#pragma unroll
    for (int d2 = 0; d2 < 32; ++d2) s += qr[d2] * ks[d2];
    Dinv_s[r][hh] = 1.f / fmaxf(s, 1e-6f);
  }
  __syncthreads();

  for (int r = 0; r < 64; ++r) {
    const float* qr = &qf[r][h * 36];
    float s = 0.f;
#pragma unroll
    for (int d2 = 0; d2 < 32; ++d2) s += qr[d2] * creg[d2];
    attnb[(row0 + r) * 256 + t] = f2bf(s * Dinv_s[r][h]);
  }
}

// ---------------------------------------------------------------------------
extern "C" void kernel_launch(void* const* d_in, const int* in_sizes, int n_in,
                              void* d_out, int out_size, void* d_ws, size_t ws_size,
                              hipStream_t stream) {
  const float* x = (const float*)d_in[0];
  const float* Wq = (const float*)d_in[1];
  const float* Wkv = (const float*)d_in[2];
  const float* Wproj = (const float*)d_in[3];
  const float* bproj = (const float*)d_in[4];
  float* out = (float*)d_out;

  char* ws = (char*)d_ws;
  unsigned short* Q = (unsigned short*)(ws);                 // 67,108,864
  unsigned short* Kb = (unsigned short*)(ws + 67108864);     // 67,108,864
  unsigned short* Vb = (unsigned short*)(ws + 134217728);    // 67,108,864
  unsigned short* wcat = (unsigned short*)(ws + 201326592);  // 393,216
  unsigned short* wpb = (unsigned short*)(ws + 201719808);   // 131,072
  unsigned short* xb = (unsigned short*)(ws + 201850880);    // 67,108,864 (dead after qkv gemm)
  float* pctx = (float*)(ws + 201850880);                    // aliases xb
  float* pksum = (float*)(ws + 206045184);
  float* ctx = (float*)(ws + 206176256);
  float* ksum = (float*)(ws + 206438400);
  unsigned short* attnb = Kb;  // reuse K buffer after ctx reduction

  const bool big = ws_size >= (size_t)268959744;

  if (big) {
    prep_all<<<17408, 256, 0, stream>>>(x, Wq, Wkv, Wproj, xb, wcat, wpb);
    gemm_bt<0><<<6144, 256, 0, stream>>>(xb, wcat, Q, Kb, Vb, nullptr, nullptr, 6);
  } else {
    prep_all<<<1024, 256, 0, stream>>>(nullptr, Wq, Wkv, Wproj, nullptr, wcat, wpb);
    gemm_qkv_f32<<<6144, 256, 0, stream>>>(x, wcat, Q, Kb, Vb, 6);
  }
  ctx_partial<<<512, 256, 0, stream>>>(Kb, Vb, pctx, pksum);
  ctx_final<<<64, 256, 0, stream>>>(pctx, pksum, ctx, ksum);
  attn_kernel<<<2048, 256, 0, stream>>>(Q, ctx, ksum, attnb);
  gemm_bt<1><<<2048, 256, 0, stream>>>(attnb, wpb, nullptr, nullptr, nullptr, out,
                                       bproj, 2);
}

// Round 7
// 306.984 us; speedup vs baseline: 1.2065x; 1.0818x over previous
//
#include <hip/hip_runtime.h>
#include <hip/hip_bf16.h>
#include <cstdint>
#include <cstddef>

typedef __attribute__((ext_vector_type(8))) short short8;
typedef __attribute__((ext_vector_type(4))) float f32x4;

#define DEVI static __device__ __forceinline__

DEVI unsigned short f2bf(float f) {
  unsigned u = __float_as_uint(f);
  unsigned r = u + 0x7fffu + ((u >> 16) & 1u);
  return (unsigned short)(r >> 16);
}
DEVI float bf2f(unsigned short s) {
  return __uint_as_float(((unsigned)s) << 16);
}
DEVI unsigned pack2(float a, float b) {
  return (unsigned)f2bf(a) | ((unsigned)f2bf(b) << 16);
}

DEVI void gload16(const void* g, void* l) {
  __builtin_amdgcn_global_load_lds(
      (__attribute__((address_space(1))) void*)g,
      (__attribute__((address_space(3))) void*)l, 16, 0, 0);
}

// ---------------------------------------------------------------------------
// prep_all: fused  x->xb bf16 (blocks 0..16383)  +  weight converts (16384..)
// ---------------------------------------------------------------------------
__global__ __launch_bounds__(256) void prep_all(
    const float* __restrict__ x, const float* __restrict__ Wq,
    const float* __restrict__ Wkv, const float* __restrict__ Wp,
    unsigned short* __restrict__ xb, unsigned short* __restrict__ wcat,
    unsigned short* __restrict__ wpb) {
  int bidx = blockIdx.x;
  if (bidx < 16384) {
    size_t i = ((size_t)bidx * 256 + threadIdx.x) * 8;
    const float4* g = (const float4*)(x + i);
    float4 a = g[0], b = g[1];
    uint4 u;
    u.x = pack2(a.x, a.y);
    u.y = pack2(a.z, a.w);
    u.z = pack2(b.x, b.y);
    u.w = pack2(b.z, b.w);
    *(uint4*)(xb + i) = u;
  } else {
    int i = (bidx - 16384) * 256 + threadIdx.x;
    if (i < 196608) {
      float v = (i < 65536) ? Wq[i] : Wkv[i - 65536];
      wcat[i] = f2bf(v);
    } else {
      int j = i - 196608;
      wpb[j] = f2bf(Wp[j]);
    }
  }
}

// ---------------------------------------------------------------------------
// QKV GEMM (round-6 proven): 6144 blocks, 4 waves, 128x128 tile, gload_lds,
// coalesced LDS-transpose epilogue. elu+1 on Q/K columns.
// ---------------------------------------------------------------------------
__global__ __launch_bounds__(256) void gemm_qkv(
    const unsigned short* __restrict__ A,
    const unsigned short* __restrict__ Bw,
    unsigned short* __restrict__ Q, unsigned short* __restrict__ Kb,
    unsigned short* __restrict__ Vb, int ntiles_n) {
  const int nwg = gridDim.x;
  const int cpx = nwg >> 3;
  const int bid = blockIdx.x;
  const int swz = (bid & 7) * cpx + (bid >> 3);
  const int bx = swz % ntiles_n, by = swz / ntiles_n;
  const int brow = by * 128, bcol = bx * 128;
  const int t = threadIdx.x, lane = t & 63, w = t >> 6;
  const int wm = w >> 1, wn = w & 1;
  const int rl = lane >> 3;
  const int swcol = (((lane & 7) ^ rl) << 4);
  const int fr = lane & 15, fq = lane >> 4;

  __shared__ __align__(16) unsigned char lds[32768];
  unsigned char* ldsA = lds;
  unsigned char* ldsB = lds + 16384;

  f32x4 acc[4][4] = {};

  for (int kt = 0; kt < 4; ++kt) {
#pragma unroll
    for (int s = 0; s < 4; ++s) {
      int row = w * 32 + s * 8;
      gload16((const char*)(A + (size_t)(brow + row + rl) * 256) + kt * 128 + swcol,
              ldsA + row * 128);
      gload16((const char*)(Bw + (size_t)(bcol + row + rl) * 256) + kt * 128 + swcol,
              ldsB + row * 128);
    }
    __syncthreads();
#pragma unroll
    for (int kk = 0; kk < 2; ++kk) {
      int kbyte = kk * 64 + fq * 16;
      short8 af[4], bfr[4];
#pragma unroll
      for (int i = 0; i < 4; ++i) {
        int ra = wm * 64 + i * 16 + fr;
        af[i] = *(const short8*)(ldsA + ra * 128 + (kbyte ^ ((ra & 7) << 4)));
        int rb = wn * 64 + i * 16 + fr;
        bfr[i] = *(const short8*)(ldsB + rb * 128 + (kbyte ^ ((rb & 7) << 4)));
      }
#pragma unroll
      for (int i = 0; i < 4; ++i)
#pragma unroll
        for (int j = 0; j < 4; ++j)
          acc[i][j] = __builtin_amdgcn_mfma_f32_16x16x32_bf16(af[i], bfr[j],
                                                              acc[i][j], 0, 0, 0);
    }
    __syncthreads();
  }

  unsigned char* wlds = lds + w * 8192;
  unsigned short* dst;
  int cofs;
  bool do_elu;
  if (bcol < 256) { dst = Q; cofs = bcol; do_elu = true; }
  else if (bcol < 512) { dst = Kb; cofs = bcol - 256; do_elu = true; }
  else { dst = Vb; cofs = bcol - 512; do_elu = false; }

#pragma unroll
  for (int i = 0; i < 4; ++i)
#pragma unroll
    for (int j = 0; j < 4; ++j)
#pragma unroll
      for (int reg = 0; reg < 4; ++reg) {
        int rloc = i * 16 + fq * 4 + reg;
        int cb = (j * 16 + fr) * 2;
        float val = acc[i][j][reg];
        if (do_elu) val = (val > 0.f) ? (val + 1.f) : __expf(val);
        *(unsigned short*)(wlds + rloc * 128 + (cb ^ ((rloc & 7) << 4))) = f2bf(val);
      }
#pragma unroll
  for (int s = 0; s < 8; ++s) {
    int rloc = s * 8 + (lane >> 3);
    int cbr = (lane & 7) * 16;
    uint4 u = *(const uint4*)(wlds + rloc * 128 + (cbr ^ ((rloc & 7) << 4)));
    *(uint4*)((char*)dst +
              ((size_t)(brow + wm * 64 + rloc) * 256 + cofs + wn * 64) * 2 + cbr) = u;
  }
}

// ---------------------------------------------------------------------------
// Fallback QKV GEMM (fp32 A, reg-stage) — only if ws too small for xb.
// ---------------------------------------------------------------------------
__global__ __launch_bounds__(256) void gemm_qkv_f32(
    const float* __restrict__ xp, const unsigned short* __restrict__ Bw,
    unsigned short* __restrict__ Q, unsigned short* __restrict__ Kb,
    unsigned short* __restrict__ Vb, int ntiles_n) {
  const int bid = blockIdx.x;
  const int bx = bid % ntiles_n, by = bid / ntiles_n;
  const int brow = by * 128, bcol = bx * 128;
  const int t = threadIdx.x;
  const int lane = t & 63, w = t >> 6;
  const int wm = w >> 1, wn = w & 1;
  __shared__ __align__(16) unsigned char ldsA[128 * 128];
  __shared__ __align__(16) unsigned char ldsB[128 * 128];
  f32x4 acc[4][4] = {};
  const int sub = t & 7, r0 = t >> 3;
  const int fr = lane & 15, fq = lane >> 4;
  for (int kt = 0; kt < 4; ++kt) {
#pragma unroll
    for (int p = 0; p < 4; ++p) {
      int row = p * 32 + r0;
      const float4* gp =
          (const float4*)(xp + (size_t)(brow + row) * 256 + kt * 64 + sub * 8);
      float4 u0 = gp[0], u1 = gp[1];
      uint4 u;
      u.x = pack2(u0.x, u0.y); u.y = pack2(u0.z, u0.w);
      u.z = pack2(u1.x, u1.y); u.w = pack2(u1.z, u1.w);
      *(uint4*)(&ldsA[row * 128 + ((sub * 16) ^ ((row & 7) << 4))]) = u;
    }
#pragma unroll
    for (int p = 0; p < 4; ++p) {
      int row = p * 32 + r0;
      uint4 u = *(const uint4*)(Bw + (size_t)(bcol + row) * 256 + kt * 64 + sub * 8);
      *(uint4*)(&ldsB[row * 128 + ((sub * 16) ^ ((row & 7) << 4))]) = u;
    }
    __syncthreads();
#pragma unroll
    for (int kk = 0; kk < 2; ++kk) {
      int kbyte = kk * 64 + fq * 16;
      short8 af[4], bfr[4];
#pragma unroll
      for (int i = 0; i < 4; ++i) {
        int ra = wm * 64 + i * 16 + fr;
        af[i] = *(const short8*)(&ldsA[ra * 128 + (kbyte ^ ((ra & 7) << 4))]);
        int rb = wn * 64 + i * 16 + fr;
        bfr[i] = *(const short8*)(&ldsB[rb * 128 + (kbyte ^ ((rb & 7) << 4))]);
      }
#pragma unroll
      for (int i = 0; i < 4; ++i)
#pragma unroll
        for (int j = 0; j < 4; ++j)
          acc[i][j] = __builtin_amdgcn_mfma_f32_16x16x32_bf16(af[i], bfr[j],
                                                              acc[i][j], 0, 0, 0);
    }
    __syncthreads();
  }
#pragma unroll
  for (int i = 0; i < 4; ++i)
#pragma unroll
    for (int j = 0; j < 4; ++j)
#pragma unroll
      for (int reg = 0; reg < 4; ++reg) {
        int gm = brow + wm * 64 + i * 16 + fq * 4 + reg;
        int gn = bcol + wn * 64 + j * 16 + fr;
        float val = acc[i][j][reg];
        if (gn < 512) val = (val > 0.f) ? (val + 1.f) : __expf(val);
        unsigned short bv = f2bf(val);
        size_t rowoff = (size_t)gm * 256;
        if (gn < 256) Q[rowoff + gn] = bv;
        else if (gn < 512) Kb[rowoff + gn - 256] = bv;
        else Vb[rowoff + gn - 512] = bv;
      }
}

// ---------------------------------------------------------------------------
// ctx partials (unchanged)
// ---------------------------------------------------------------------------
__global__ __launch_bounds__(256) void ctx_partial(
    const unsigned short* __restrict__ Kb, const unsigned short* __restrict__ Vb,
    float* __restrict__ pctx, float* __restrict__ pksum) {
  const int blk = blockIdx.x;
  const int b = blk >> 6;
  const int hp = (blk >> 4) & 3;
  const int chunk = blk & 15;
  const int t = threadIdx.x;
  const size_t rowbase = (size_t)b * 16384 + (size_t)chunk * 1024;
  const int colbase = hp * 64;

  __shared__ __align__(16) unsigned short kt_[64][64];
  __shared__ __align__(16) unsigned short vt_[64][64];

  const int d = t >> 3;
  const int e4 = (t & 7) * 4;
  float a0[4] = {0.f, 0.f, 0.f, 0.f}, a1[4] = {0.f, 0.f, 0.f, 0.f};
  float ks0 = 0.f, ks1 = 0.f;

  const int lrow = t >> 3;
  const int lcol = (t & 7) * 8;
  for (int pass = 0; pass < 16; ++pass) {
#pragma unroll
    for (int hf = 0; hf < 2; ++hf) {
      size_t row = rowbase + pass * 64 + hf * 32 + lrow;
      *(uint4*)&kt_[hf * 32 + lrow][lcol] = *(const uint4*)(Kb + row * 256 + colbase + lcol);
      *(uint4*)&vt_[hf * 32 + lrow][lcol] = *(const uint4*)(Vb + row * 256 + colbase + lcol);
    }
    __syncthreads();
#pragma unroll 4
    for (int n = 0; n < 64; ++n) {
      float k0 = bf2f(kt_[n][d]);
      float k1 = bf2f(kt_[n][32 + d]);
      if ((t & 7) == 0) { ks0 += k0; ks1 += k1; }
      uint2 w0 = *(const uint2*)&vt_[n][e4];
      uint2 w1 = *(const uint2*)&vt_[n][32 + e4];
      float v00 = __uint_as_float(w0.x << 16), v01 = __uint_as_float(w0.x & 0xffff0000u);
      float v02 = __uint_as_float(w0.y << 16), v03 = __uint_as_float(w0.y & 0xffff0000u);
      float v10 = __uint_as_float(w1.x << 16), v11 = __uint_as_float(w1.x & 0xffff0000u);
      float v12 = __uint_as_float(w1.y << 16), v13 = __uint_as_float(w1.y & 0xffff0000u);
      a0[0] += k0 * v00; a0[1] += k0 * v01; a0[2] += k0 * v02; a0[3] += k0 * v03;
      a1[0] += k1 * v10; a1[1] += k1 * v11; a1[2] += k1 * v12; a1[3] += k1 * v13;
    }
    __syncthreads();
  }
  float* p0 = pctx + (size_t)blk * 2048 + d * 32 + e4;
  p0[0] = a0[0]; p0[1] = a0[1]; p0[2] = a0[2]; p0[3] = a0[3];
  float* p1 = p0 + 1024;
  p1[0] = a1[0]; p1[1] = a1[1]; p1[2] = a1[2]; p1[3] = a1[3];
  if ((t & 7) == 0) {
    pksum[blk * 64 + d] = ks0;
    pksum[blk * 64 + 32 + d] = ks1;
  }
}

// ---------------------------------------------------------------------------
// ctx final reduce -> ctxT bf16 hi/lo pair [bh][{hi,lo}][e][d]  +  ksum fp32
// ---------------------------------------------------------------------------
__global__ __launch_bounds__(256) void ctx_final(
    const float* __restrict__ pctx, const float* __restrict__ pksum,
    unsigned short* __restrict__ ctxT, float* __restrict__ ksum) {
  int bh = blockIdx.x;
  int b = bh >> 3, h = bh & 7, hp = h >> 1, hh = h & 1;
  int t = threadIdx.x;
  int d = t >> 3, e4 = (t & 7) * 4;
  float s[4] = {0.f, 0.f, 0.f, 0.f};
  for (int j = 0; j < 16; ++j) {
    const float* p = pctx + ((size_t)((b * 4 + hp) * 16 + j)) * 2048 + hh * 1024 + t * 4;
    s[0] += p[0]; s[1] += p[1]; s[2] += p[2]; s[3] += p[3];
  }
  unsigned short* cc = ctxT + (size_t)bh * 2048;
#pragma unroll
  for (int e2 = 0; e2 < 4; ++e2) {
    int e = e4 + e2;
    unsigned short hi = f2bf(s[e2]);
    float lo = s[e2] - bf2f(hi);
    cc[e * 32 + d] = hi;
    cc[1024 + e * 32 + d] = f2bf(lo);
  }
  if (t < 32) {
    float ss = 0.f;
    for (int j = 0; j < 16; ++j) ss += pksum[((b * 4 + hp) * 16 + j) * 64 + hh * 32 + t];
    ksum[bh * 32 + t] = ss;
  }
}

// ---------------------------------------------------------------------------
// FUSED attn + out-projection.  1024 blocks (128-row panels), 512 threads.
//   1. stage Q panel [128][256] bf16 -> qa (XOR-swz), ctxT hi/lo -> wpB[1],
//      ksum -> ksumL
//   2. Dinv[r][h] = 1/max(q.ksum, 1e-6)  (VALU, fp32)
//   3. S = q @ ctx per head via MFMA (hi+lo), scale by Dinv, f2bf -> qa
//      (in-place, A-layout)
//   4. out = attn @ Wp^T + bias: Wp streamed in 4 quarter-tiles (ping-pong),
//      fp32 epilogue coalesced through the idle buffer (256B/row stores)
// ---------------------------------------------------------------------------
__global__ __launch_bounds__(512) void attn_proj(
    const unsigned short* __restrict__ Q,
    const unsigned short* __restrict__ ctxT,
    const float* __restrict__ ksum,
    const unsigned short* __restrict__ wpb,
    const float* __restrict__ bias,
    float* __restrict__ out) {
  const int t = threadIdx.x;
  const int lane = t & 63, w = t >> 6;  // 8 waves
  const int panel = blockIdx.x;         // 1024
  const int b = panel >> 7;
  const size_t row0 = (size_t)panel * 128;
  const int l5 = lane & 31;
  const int rpar = lane >> 5;
  const int fr = lane & 15, fq = lane >> 4;

  __shared__ __align__(16) unsigned char qa[65536];      // [128][512B] swz
  __shared__ __align__(16) unsigned char wpB[2][32768];  // ping-pong / ctx / scratch
  __shared__ float ksumL[256];
  __shared__ float Dinv_s[128][8];

  // ---- stage: q panel (8 segs/wave), ctxT (4 segs/wave -> wpB[1]), ksum ----
#pragma unroll
  for (int s = 0; s < 8; ++s) {
    int seg = w * 8 + s;
    int row = seg * 2 + rpar;
    gload16((const char*)Q + (row0 + row) * 512 + ((l5 * 16) ^ ((row & 7) << 4)),
            qa + seg * 1024);
  }
#pragma unroll
  for (int s = 0; s < 4; ++s) {
    int seg = w * 4 + s;
    gload16((const char*)ctxT + (size_t)b * 32768 + seg * 1024 + lane * 16,
            wpB[1] + seg * 1024);
  }
  if (w == 0) gload16((const char*)(ksum + b * 256) + lane * 16, (void*)ksumL);
  __syncthreads();

  // ---- Dinv: 1024 (row,head) pairs, 2 per thread ----
#pragma unroll
  for (int ii = 0; ii < 2; ++ii) {
    int p = t + ii * 512;
    int r = p >> 3, h = p & 7;
    const unsigned char* qrow = qa + r * 512;
    int swzr = (r & 7) << 4;
    float s = 0.f;
#pragma unroll
    for (int dd = 0; dd < 16; ++dd) {
      unsigned u = *(const unsigned*)(qrow + ((h * 64 + dd * 4) ^ swzr));
      s += __uint_as_float(u << 16) * ksumL[h * 32 + dd * 2] +
           __uint_as_float(u & 0xffff0000u) * ksumL[h * 32 + dd * 2 + 1];
    }
    Dinv_s[r][h] = 1.f / fmaxf(s, 1e-6f);
  }

  // ---- S = q @ ctx (per head, K=32, hi+lo MFMA) ----
  const int wrow = w >> 2, cw = w & 3;  // wave: rows wrow*64.., heads 2cw,2cw+1
  f32x4 sacc[2][4][2];
#pragma unroll
  for (int h2 = 0; h2 < 2; ++h2)
#pragma unroll
    for (int i = 0; i < 4; ++i)
#pragma unroll
      for (int j = 0; j < 2; ++j)
#pragma unroll
        for (int c = 0; c < 4; ++c) sacc[h2][i][j][c] = 0.f;

#pragma unroll
  for (int h2 = 0; h2 < 2; ++h2) {
    int h = 2 * cw + h2;
#pragma unroll
    for (int i = 0; i < 4; ++i) {
      int ra = wrow * 64 + i * 16 + fr;
      short8 af = *(const short8*)(qa + ra * 512 +
                                   ((h * 64 + fq * 16) ^ ((ra & 7) << 4)));
#pragma unroll
      for (int j = 0; j < 2; ++j) {
        int rb = j * 16 + fr;
        short8 bhi = *(const short8*)(wpB[1] + h * 4096 + rb * 64 + fq * 16);
        short8 blo = *(const short8*)(wpB[1] + h * 4096 + 2048 + rb * 64 + fq * 16);
        sacc[h2][i][j] = __builtin_amdgcn_mfma_f32_16x16x32_bf16(
            af, bhi, sacc[h2][i][j], 0, 0, 0);
        sacc[h2][i][j] = __builtin_amdgcn_mfma_f32_16x16x32_bf16(
            af, blo, sacc[h2][i][j], 0, 0, 0);
      }
    }
  }
  __syncthreads();  // all S reads of qa done

  // ---- scale by Dinv, write attn bf16 back into qa (A-layout, swz) ----
#pragma unroll
  for (int h2 = 0; h2 < 2; ++h2) {
    int h = 2 * cw + h2;
#pragma unroll
    for (int i = 0; i < 4; ++i)
#pragma unroll
      for (int j = 0; j < 2; ++j)
#pragma unroll
        for (int reg = 0; reg < 4; ++reg) {
          int r = wrow * 64 + i * 16 + fq * 4 + reg;
          int c = h * 32 + j * 16 + fr;
          float v = sacc[h2][i][j][reg] * Dinv_s[r][h];
          *(unsigned short*)(qa + r * 512 + ((2 * c) ^ ((r & 7) << 4))) = f2bf(v);
        }
  }

  // ---- out = attn @ Wp^T + bias, 4 quarter-tiles of 64 out-cols ----
  for (int q = 0; q < 4; ++q) {
    unsigned char* wbuf = wpB[q & 1];
    unsigned char* scr = wpB[(q & 1) ^ 1];
    // stage Wp quarter (rows q*64..q*64+64), 4 segs/wave
#pragma unroll
    for (int s = 0; s < 4; ++s) {
      int seg = w * 4 + s;
      int rowl = seg * 2 + rpar;
      gload16((const char*)wpb + (size_t)(q * 64 + rowl) * 512 +
                  ((l5 * 16) ^ ((rowl & 7) << 4)),
              wbuf + seg * 1024);
    }
    __syncthreads();  // stage visible; also fences qa writeback on q==0

    // MFMA: wave w -> rows w*16..w*16+16, cols q*64..q*64+64
    f32x4 oacc[4];
#pragma unroll
    for (int j = 0; j < 4; ++j)
#pragma unroll
      for (int c = 0; c < 4; ++c) oacc[j][c] = 0.f;
    const int ra = w * 16 + fr;
    const int sra = (ra & 7) << 4;
#pragma unroll
    for (int kk = 0; kk < 8; ++kk) {
      short8 af = *(const short8*)(qa + ra * 512 + ((kk * 64 + fq * 16) ^ sra));
#pragma unroll
      for (int j = 0; j < 4; ++j) {
        int rb = j * 16 + fr;
        short8 bf8 = *(const short8*)(wbuf + rb * 512 +
                                      ((kk * 64 + fq * 16) ^ ((rb & 7) << 4)));
        oacc[j] = __builtin_amdgcn_mfma_f32_16x16x32_bf16(af, bf8, oacc[j], 0, 0, 0);
      }
    }
    // bias + coalesced epilogue via wave-private 4KB of scr
    unsigned char* ws4 = scr + w * 4096;
#pragma unroll
    for (int j = 0; j < 4; ++j) {
      float bj = bias[q * 64 + j * 16 + fr];
#pragma unroll
      for (int reg = 0; reg < 4; ++reg) {
        int ri = fq * 4 + reg;
        int cb = (j * 16 + fr) * 4;
        *(float*)(ws4 + ri * 256 + (cb ^ ((ri & 7) << 4))) = oacc[j][reg] + bj;
      }
    }
#pragma unroll
    for (int c = 0; c < 4; ++c) {
      int ri = lane >> 2;
      int cb = (lane & 3) * 16 + c * 64;
      uint4 u = *(const uint4*)(ws4 + ri * 256 + (cb ^ ((ri & 7) << 4)));
      *(uint4*)((char*)(out + (row0 + w * 16 + ri) * 256 + q * 64) + cb) = u;
    }
    __syncthreads();  // protect scr before next-iter staging overwrites it
  }
}

// ---------------------------------------------------------------------------
extern "C" void kernel_launch(void* const* d_in, const int* in_sizes, int n_in,
                              void* d_out, int out_size, void* d_ws, size_t ws_size,
                              hipStream_t stream) {
  const float* x = (const float*)d_in[0];
  const float* Wq = (const float*)d_in[1];
  const float* Wkv = (const float*)d_in[2];
  const float* Wproj = (const float*)d_in[3];
  const float* bproj = (const float*)d_in[4];
  float* out = (float*)d_out;

  char* ws = (char*)d_ws;
  unsigned short* Q = (unsigned short*)(ws);                 // 67,108,864
  unsigned short* Kb = (unsigned short*)(ws + 67108864);     // 67,108,864
  unsigned short* Vb = (unsigned short*)(ws + 134217728);    // 67,108,864
  unsigned short* wcat = (unsigned short*)(ws + 201326592);  // 393,216
  unsigned short* wpb = (unsigned short*)(ws + 201719808);   // 131,072
  unsigned short* xb = (unsigned short*)(ws + 201850880);    // 67,108,864 (dead after qkv)
  float* pctx = (float*)(ws + 201850880);                    // aliases xb
  float* pksum = (float*)(ws + 206045184);
  float* ksum = (float*)(ws + 206438400);                    // 8,192
  unsigned short* ctxT = (unsigned short*)(ws + 206446592);  // 262,144 bf16 hi/lo

  const bool big = ws_size >= (size_t)268959744;

  if (big) {
    prep_all<<<17408, 256, 0, stream>>>(x, Wq, Wkv, Wproj, xb, wcat, wpb);
    gemm_qkv<<<6144, 256, 0, stream>>>(xb, wcat, Q, Kb, Vb, 6);
  } else {
    prep_all<<<1024, 256, 0, stream>>>(nullptr, Wq, Wkv, Wproj, nullptr, wcat, wpb);
    gemm_qkv_f32<<<6144, 256, 0, stream>>>(x, wcat, Q, Kb, Vb, 6);
  }
  ctx_partial<<<512, 256, 0, stream>>>(Kb, Vb, pctx, pksum);
  ctx_final<<<64, 256, 0, stream>>>(pctx, pksum, ctxT, ksum);
  attn_proj<<<1024, 512, 0, stream>>>(Q, ctxT, ksum, wpb, bproj, out);
}

// Round 8
// 265.257 us; speedup vs baseline: 1.3962x; 1.1573x over previous
//
#include <hip/hip_runtime.h>
#include <hip/hip_bf16.h>
#include <cstdint>
#include <cstddef>

typedef __attribute__((ext_vector_type(8))) short short8;
typedef __attribute__((ext_vector_type(4))) float f32x4;

#define DEVI static __device__ __forceinline__

DEVI unsigned short f2bf(float f) {
  unsigned u = __float_as_uint(f);
  unsigned r = u + 0x7fffu + ((u >> 16) & 1u);
  return (unsigned short)(r >> 16);
}
DEVI float bf2f(unsigned short s) {
  return __uint_as_float(((unsigned)s) << 16);
}
DEVI unsigned pack2(float a, float b) {
  return (unsigned)f2bf(a) | ((unsigned)f2bf(b) << 16);
}

DEVI void gload16(const void* g, void* l) {
  __builtin_amdgcn_global_load_lds(
      (__attribute__((address_space(1))) void*)g,
      (__attribute__((address_space(3))) void*)l, 16, 0, 0);
}

// ---------------------------------------------------------------------------
// prep_w: Wq/Wkv -> wcat bf16 [768][256], Wproj -> wpb bf16 [256][256]
// ---------------------------------------------------------------------------
__global__ __launch_bounds__(256) void prep_w(
    const float* __restrict__ Wq, const float* __restrict__ Wkv,
    const float* __restrict__ Wp, unsigned short* __restrict__ wcat,
    unsigned short* __restrict__ wpb) {
  int i = blockIdx.x * 256 + threadIdx.x;  // grid 1024
  if (i < 196608) {
    float v = (i < 65536) ? Wq[i] : Wkv[i - 65536];
    wcat[i] = f2bf(v);
  } else {
    int j = i - 196608;
    wpb[j] = f2bf(Wp[j]);
  }
}

// ---------------------------------------------------------------------------
// MEGA: per 64-row panel: x->bf16 LDS inline; 24 W-slivers (32 cols each):
//  s0..7  = Q cols (elu, coalesced global store via LDS bounce)
//  s8+2h  = K head h (elu, -> kT LDS transposed)
//  s9+2h  = V head h (-> vT LDS transposed); ctx+ksum MFMA per head after.
// pctx[panel][h][32d][32e] fp32 partials + pksum[panel][h][32d].
// 2048 blocks x 256 thr (4 waves), 72KB LDS -> 2 blocks/CU.
// ---------------------------------------------------------------------------
__global__ __launch_bounds__(256) void qkv_ctx(
    const float* __restrict__ x, const unsigned short* __restrict__ wcat,
    unsigned short* __restrict__ Q, float* __restrict__ pctx,
    float* __restrict__ pksum) {
  const int t = threadIdx.x;
  const int lane = t & 63, w = t >> 6;  // 4 waves
  const int p = blockIdx.x;             // 2048 panels of 64 rows
  const size_t row0 = (size_t)p * 64;
  const int fr = lane & 15, fq = lane >> 4;

  __shared__ __align__(16) unsigned char smem[73728];
  unsigned char* xa = smem;              // 32KB [64][512B] ^((r&7)<<4)
  unsigned char* wb0 = smem + 32768;     // 16KB [32][512B]
  unsigned char* wb1 = smem + 49152;     // 16KB
  unsigned char* kT = smem + 65536;      // 4KB [32 d][128B] ^((d&7)<<4)
  unsigned char* vT = smem + 69632;      // 4KB

  const short ob = (short)0x3F80;
  const short8 ones = {ob, ob, ob, ob, ob, ob, ob, ob};

  // ---- stage xa: fp32 -> bf16, swizzled ----
  {
    int r = t >> 2, qt = t & 3;
    const float* xrow = x + (row0 + r) * 256 + qt * 64;
    unsigned char* dstr = xa + r * 512;
    int swz = (r & 7) << 4;
#pragma unroll
    for (int i = 0; i < 8; ++i) {
      float4 a = *(const float4*)(xrow + i * 8);
      float4 b = *(const float4*)(xrow + i * 8 + 4);
      uint4 u;
      u.x = pack2(a.x, a.y);
      u.y = pack2(a.z, a.w);
      u.z = pack2(b.x, b.y);
      u.w = pack2(b.z, b.w);
      *(uint4*)(dstr + ((qt * 128 + i * 16) ^ swz)) = u;
    }
  }

  auto stage_w = [&](unsigned char* buf, int s) {
    int wr0 = (s < 8) ? s * 32
                      : (((s & 1) == 0) ? 256 + ((s - 8) >> 1) * 32
                                        : 512 + ((s - 8) >> 1) * 32);
#pragma unroll
    for (int i = 0; i < 4; ++i) {
      int seg = w * 4 + i;
      int rloc = seg * 2 + (lane >> 5);
      gload16((const char*)wcat + (size_t)(wr0 + rloc) * 512 +
                  (((lane & 31) * 16) ^ ((rloc & 7) << 4)),
              buf + seg * 1024);
    }
  };

  auto ctx_head = [&](int h) {
    const int dp = w >> 1, ep = w & 1;
    f32x4 cacc = {0.f, 0.f, 0.f, 0.f};
    f32x4 sacc = {0.f, 0.f, 0.f, 0.f};
    const int rka = dp * 16 + fr;
    const int rkb = ep * 16 + fr;
#pragma unroll
    for (int ks = 0; ks < 2; ++ks) {
      short8 ak = *(const short8*)(kT + rka * 128 +
                                   ((ks * 64 + fq * 16) ^ ((rka & 7) << 4)));
      short8 bv = *(const short8*)(vT + rkb * 128 +
                                   ((ks * 64 + fq * 16) ^ ((rkb & 7) << 4)));
      cacc = __builtin_amdgcn_mfma_f32_16x16x32_bf16(ak, bv, cacc, 0, 0, 0);
      if (ep == 0)
        sacc = __builtin_amdgcn_mfma_f32_16x16x32_bf16(ak, ones, sacc, 0, 0, 0);
    }
    float* pc = pctx + ((size_t)(p * 8 + h)) * 1024;
#pragma unroll
    for (int reg = 0; reg < 4; ++reg) {
      int d = dp * 16 + fq * 4 + reg;
      int e = ep * 16 + fr;
      pc[d * 32 + e] = cacc[reg];
    }
    if (ep == 0 && fr == 0) {
#pragma unroll
      for (int reg = 0; reg < 4; ++reg) {
        int d = dp * 16 + fq * 4 + reg;
        pksum[((size_t)(p * 8 + h)) * 32 + d] = sacc[reg];
      }
    }
  };

  stage_w(wb0, 0);
  __syncthreads();

  const int ra = w * 16 + fr;
  const int sra = (ra & 7) << 4;

  for (int s = 0; s < 24; ++s) {
    if (s >= 10 && (s & 1) == 0) ctx_head((s - 10) >> 1);
    if (s < 23) stage_w(((s & 1) == 0) ? wb1 : wb0, s + 1);

    const unsigned char* wbuf = ((s & 1) == 0) ? wb0 : wb1;
    f32x4 acc[2] = {{0.f, 0.f, 0.f, 0.f}, {0.f, 0.f, 0.f, 0.f}};
#pragma unroll
    for (int ks = 0; ks < 8; ++ks) {
      short8 af = *(const short8*)(xa + ra * 512 + ((ks * 64 + fq * 16) ^ sra));
#pragma unroll
      for (int j = 0; j < 2; ++j) {
        int rb = j * 16 + fr;
        short8 bf8 = *(const short8*)(wbuf + rb * 512 +
                                      ((ks * 64 + fq * 16) ^ ((rb & 7) << 4)));
        acc[j] = __builtin_amdgcn_mfma_f32_16x16x32_bf16(af, bf8, acc[j], 0, 0, 0);
      }
    }
    if (s >= 8) __syncthreads();  // ctx readers done before kT/vT overwrite

    if (s < 8) {
      // Q epilogue: wave-private 1KB bounce in kT/vT area -> coalesced store
      unsigned char* scr = kT + w * 1024;
#pragma unroll
      for (int j = 0; j < 2; ++j)
#pragma unroll
        for (int reg = 0; reg < 4; ++reg) {
          int rloc = fq * 4 + reg;
          float v = acc[j][reg];
          v = (v > 0.f) ? (v + 1.f) : __expf(v);
          *(unsigned short*)(scr + rloc * 64 +
                             (((j * 16 + fr) * 2) ^ ((rloc & 3) << 4))) = f2bf(v);
        }
      int rowq = lane >> 2;
      uint4 u = *(const uint4*)(scr + rowq * 64 +
                                (((lane & 3) * 16) ^ ((rowq & 3) << 4)));
      *(uint4*)((char*)Q + (row0 + w * 16 + rowq) * 512 + s * 64 +
                (lane & 3) * 16) = u;
    } else {
      unsigned char* dstT = ((s & 1) == 0) ? kT : vT;
      bool elu = ((s & 1) == 0);
#pragma unroll
      for (int j = 0; j < 2; ++j)
#pragma unroll
        for (int reg = 0; reg < 4; ++reg) {
          int n = w * 16 + fq * 4 + reg;  // 0..63
          int d = j * 16 + fr;            // 0..31
          float v = acc[j][reg];
          if (elu) v = (v > 0.f) ? (v + 1.f) : __expf(v);
          *(unsigned short*)(dstT + d * 128 + ((n * 2) ^ ((d & 7) << 4))) = f2bf(v);
        }
    }
    __syncthreads();
  }
  ctx_head(7);
}

// ---------------------------------------------------------------------------
// ctx_final2: reduce 256 panel-partials per (b,h) -> ctxT bf16 hi/lo + ksum
// ---------------------------------------------------------------------------
__global__ __launch_bounds__(256) void ctx_final2(
    const float* __restrict__ pctx, const float* __restrict__ pksum,
    unsigned short* __restrict__ ctxT, float* __restrict__ ksum) {
  int bh = blockIdx.x;
  int b = bh >> 3, h = bh & 7;
  int t = threadIdx.x;
  int d = t >> 3, e4 = (t & 7) * 4;
  float s[4] = {0.f, 0.f, 0.f, 0.f};
  for (int pp = 0; pp < 256; ++pp) {
    const float* q = pctx + ((size_t)((b * 256 + pp) * 8 + h)) * 1024 + d * 32 + e4;
    s[0] += q[0]; s[1] += q[1]; s[2] += q[2]; s[3] += q[3];
  }
  unsigned short* cc = ctxT + (size_t)bh * 2048;
#pragma unroll
  for (int e2 = 0; e2 < 4; ++e2) {
    int e = e4 + e2;
    unsigned short hi = f2bf(s[e2]);
    float lo = s[e2] - bf2f(hi);
    cc[e * 32 + d] = hi;
    cc[1024 + e * 32 + d] = f2bf(lo);
  }
  __shared__ float ksp[8][32];
  int d2 = t & 31, ch = t >> 5;
  float ss = 0.f;
  for (int pp = ch; pp < 256; pp += 8)
    ss += pksum[((size_t)((b * 256 + pp) * 8 + h)) * 32 + d2];
  ksp[ch][d2] = ss;
  __syncthreads();
  if (t < 32) {
    float r = 0.f;
#pragma unroll
    for (int c = 0; c < 8; ++c) r += ksp[c][t];
    ksum[bh * 32 + t] = r;
  }
}

// ---------------------------------------------------------------------------
// FUSED attn + out-projection (round-7 proven, unchanged).
// ---------------------------------------------------------------------------
__global__ __launch_bounds__(512) void attn_proj(
    const unsigned short* __restrict__ Q,
    const unsigned short* __restrict__ ctxT,
    const float* __restrict__ ksum,
    const unsigned short* __restrict__ wpb,
    const float* __restrict__ bias,
    float* __restrict__ out) {
  const int t = threadIdx.x;
  const int lane = t & 63, w = t >> 6;  // 8 waves
  const int panel = blockIdx.x;         // 1024
  const int b = panel >> 7;
  const size_t row0 = (size_t)panel * 128;
  const int l5 = lane & 31;
  const int rpar = lane >> 5;
  const int fr = lane & 15, fq = lane >> 4;

  __shared__ __align__(16) unsigned char qa[65536];
  __shared__ __align__(16) unsigned char wpB[2][32768];
  __shared__ float ksumL[256];
  __shared__ float Dinv_s[128][8];

#pragma unroll
  for (int s = 0; s < 8; ++s) {
    int seg = w * 8 + s;
    int row = seg * 2 + rpar;
    gload16((const char*)Q + (row0 + row) * 512 + ((l5 * 16) ^ ((row & 7) << 4)),
            qa + seg * 1024);
  }
#pragma unroll
  for (int s = 0; s < 4; ++s) {
    int seg = w * 4 + s;
    gload16((const char*)ctxT + (size_t)b * 32768 + seg * 1024 + lane * 16,
            wpB[1] + seg * 1024);
  }
  if (w == 0) gload16((const char*)(ksum + b * 256) + lane * 16, (void*)ksumL);
  __syncthreads();

#pragma unroll
  for (int ii = 0; ii < 2; ++ii) {
    int pp = t + ii * 512;
    int r = pp >> 3, h = pp & 7;
    const unsigned char* qrow = qa + r * 512;
    int swzr = (r & 7) << 4;
    float s = 0.f;
#pragma unroll
    for (int dd = 0; dd < 16; ++dd) {
      unsigned u = *(const unsigned*)(qrow + ((h * 64 + dd * 4) ^ swzr));
      s += __uint_as_float(u << 16) * ksumL[h * 32 + dd * 2] +
           __uint_as_float(u & 0xffff0000u) * ksumL[h * 32 + dd * 2 + 1];
    }
    Dinv_s[r][h] = 1.f / fmaxf(s, 1e-6f);
  }

  const int wrow = w >> 2, cw = w & 3;
  f32x4 sacc[2][4][2];
#pragma unroll
  for (int h2 = 0; h2 < 2; ++h2)
#pragma unroll
    for (int i = 0; i < 4; ++i)
#pragma unroll
      for (int j = 0; j < 2; ++j)
#pragma unroll
        for (int c = 0; c < 4; ++c) sacc[h2][i][j][c] = 0.f;

#pragma unroll
  for (int h2 = 0; h2 < 2; ++h2) {
    int h = 2 * cw + h2;
#pragma unroll
    for (int i = 0; i < 4; ++i) {
      int ra = wrow * 64 + i * 16 + fr;
      short8 af = *(const short8*)(qa + ra * 512 +
                                   ((h * 64 + fq * 16) ^ ((ra & 7) << 4)));
#pragma unroll
      for (int j = 0; j < 2; ++j) {
        int rb = j * 16 + fr;
        short8 bhi = *(const short8*)(wpB[1] + h * 4096 + rb * 64 + fq * 16);
        short8 blo = *(const short8*)(wpB[1] + h * 4096 + 2048 + rb * 64 + fq * 16);
        sacc[h2][i][j] = __builtin_amdgcn_mfma_f32_16x16x32_bf16(
            af, bhi, sacc[h2][i][j], 0, 0, 0);
        sacc[h2][i][j] = __builtin_amdgcn_mfma_f32_16x16x32_bf16(
            af, blo, sacc[h2][i][j], 0, 0, 0);
      }
    }
  }
  __syncthreads();

#pragma unroll
  for (int h2 = 0; h2 < 2; ++h2) {
    int h = 2 * cw + h2;
#pragma unroll
    for (int i = 0; i < 4; ++i)
#pragma unroll
      for (int j = 0; j < 2; ++j)
#pragma unroll
        for (int reg = 0; reg < 4; ++reg) {
          int r = wrow * 64 + i * 16 + fq * 4 + reg;
          int c = h * 32 + j * 16 + fr;
          float v = sacc[h2][i][j][reg] * Dinv_s[r][h];
          *(unsigned short*)(qa + r * 512 + ((2 * c) ^ ((r & 7) << 4))) = f2bf(v);
        }
  }

  for (int q = 0; q < 4; ++q) {
    unsigned char* wbuf = wpB[q & 1];
    unsigned char* scr = wpB[(q & 1) ^ 1];
#pragma unroll
    for (int s = 0; s < 4; ++s) {
      int seg = w * 4 + s;
      int rowl = seg * 2 + rpar;
      gload16((const char*)wpb + (size_t)(q * 64 + rowl) * 512 +
                  ((l5 * 16) ^ ((rowl & 7) << 4)),
              wbuf + seg * 1024);
    }
    __syncthreads();

    f32x4 oacc[4];
#pragma unroll
    for (int j = 0; j < 4; ++j)
#pragma unroll
      for (int c = 0; c < 4; ++c) oacc[j][c] = 0.f;
    const int ra = w * 16 + fr;
    const int sra = (ra & 7) << 4;
#pragma unroll
    for (int kk = 0; kk < 8; ++kk) {
      short8 af = *(const short8*)(qa + ra * 512 + ((kk * 64 + fq * 16) ^ sra));
#pragma unroll
      for (int j = 0; j < 4; ++j) {
        int rb = j * 16 + fr;
        short8 bf8 = *(const short8*)(wbuf + rb * 512 +
                                      ((kk * 64 + fq * 16) ^ ((rb & 7) << 4)));
        oacc[j] = __builtin_amdgcn_mfma_f32_16x16x32_bf16(af, bf8, oacc[j], 0, 0, 0);
      }
    }
    unsigned char* ws4 = scr + w * 4096;
#pragma unroll
    for (int j = 0; j < 4; ++j) {
      float bj = bias[q * 64 + j * 16 + fr];
#pragma unroll
      for (int reg = 0; reg < 4; ++reg) {
        int ri = fq * 4 + reg;
        int cb = (j * 16 + fr) * 4;
        *(float*)(ws4 + ri * 256 + (cb ^ ((ri & 7) << 4))) = oacc[j][reg] + bj;
      }
    }
#pragma unroll
    for (int c = 0; c < 4; ++c) {
      int ri = lane >> 2;
      int cb = (lane & 3) * 16 + c * 64;
      uint4 u = *(const uint4*)(ws4 + ri * 256 + (cb ^ ((ri & 7) << 4)));
      *(uint4*)((char*)(out + (row0 + w * 16 + ri) * 256 + q * 64) + cb) = u;
    }
    __syncthreads();
  }
}

// ---------------------------------------------------------------------------
extern "C" void kernel_launch(void* const* d_in, const int* in_sizes, int n_in,
                              void* d_out, int out_size, void* d_ws, size_t ws_size,
                              hipStream_t stream) {
  const float* x = (const float*)d_in[0];
  const float* Wq = (const float*)d_in[1];
  const float* Wkv = (const float*)d_in[2];
  const float* Wproj = (const float*)d_in[3];
  const float* bproj = (const float*)d_in[4];
  float* out = (float*)d_out;

  char* ws = (char*)d_ws;
  unsigned short* Q = (unsigned short*)(ws);                  // 67,108,864
  unsigned short* wcat = (unsigned short*)(ws + 67108864);    // 393,216
  unsigned short* wpb = (unsigned short*)(ws + 67502080);     // 131,072
  float* pctx = (float*)(ws + 67633152);                      // 67,108,864
  float* pksum = (float*)(ws + 134742016);                    // 2,097,152
  unsigned short* ctxT = (unsigned short*)(ws + 136839168);   // 262,144
  float* ksum = (float*)(ws + 137101312);                     // 8,192

  prep_w<<<1024, 256, 0, stream>>>(Wq, Wkv, Wproj, wcat, wpb);
  qkv_ctx<<<2048, 256, 0, stream>>>(x, wcat, Q, pctx, pksum);
  ctx_final2<<<64, 256, 0, stream>>>(pctx, pksum, ctxT, ksum);
  attn_proj<<<1024, 512, 0, stream>>>(Q, ctxT, ksum, wpb, bproj, out);
}